// Round 4
// baseline (182.901 us; speedup 1.0000x reference)
//
#include <hip/hip_runtime.h>
#include <math.h>

#define NS2 0.70710678118654752440f  // 1/sqrt(2)
#define NS3 0.57735026918962576451f  // 1/sqrt(3)
#define NS6 0.40824829046386301636f  // 1/sqrt(6)

// ws layout (float offsets)
// W2: [352 iterations][64 lanes][8] — iteration-ordered collapsed weights
//   it 0..63    P1: c = it*64+l            (W3_0 row c, Wout col o*7+k)         v=b0[l], u=a0[it]
//   it 64..159  P4: s=it-64,m=s>>5,a=s&31  (W3_1 row 2048+a*64+l, col 64+o*3+m) v=b0[l], u=A1[a]*d_m
//   it 160..351 b32: it2=it-160, ah=l>>5, bh=l&31:
//     it2 0..15   P2: a=it2*2+ah    (W3_0 row 4096+a*32+bh)                     v=B1[bh], u=A1[a]*NS3dd
//     it2 16..111 P3: u2=it2-16,m=u2>>5,a=(u2&31)*2+ah (W3_1 row a*32+bh, col 64+o*3+m)  u=a0[a]*d_m
//     it2 112..191P5: u2=it2-112,m=u2>>4,a=(u2&15)*2+ah (W3_2 row a*32+bh, col 160+o*5+m) u=A1[a]*q_m
#define OFF_W2   0
#define OFF_FEAT 180224   // [N/8 groups][208 rows][8 nodes]: a0 0-63, b0 64-127, A1 128-159, B1 160-191, geom 192-200
#define FEAT_STRIDE 1664

// prep: blocks 0..87 build W2; blocks 88.. build per-group features + bias-init out
__global__ __launch_bounds__(256) void prep_kernel(
    const float* __restrict__ pos,
    const float* __restrict__ W1_0, const float* __restrict__ W1_1,
    const float* __restrict__ W2_0, const float* __restrict__ W2_1,
    const float* __restrict__ W3_0, const float* __restrict__ W3_1,
    const float* __restrict__ W3_2, const float* __restrict__ Wout,
    const float* __restrict__ bout,
    float* __restrict__ ws, float* __restrict__ out, int N)
{
    __shared__ float s_wo[1680];
    __shared__ float s_f0[8][64];
    __shared__ float s_f1[8][32];
    const int tid = threadIdx.x;

    if (blockIdx.x < 88) {
        // ---------------- weight build ----------------
        for (int i = tid; i < 1680; i += 256) s_wo[i] = Wout[i];
        __syncthreads();
        int R = blockIdx.x * 256 + tid;          // 0..22527
        int it = R >> 6, l = R & 63;
        float acc[7] = {0.f,0.f,0.f,0.f,0.f,0.f,0.f};
        if (it < 64) {                            // P1
            const float* wr = W3_0 + (it*64 + l) * 64;
            #pragma unroll 4
            for (int o = 0; o < 64; o += 4) {
                float4 wv = *(const float4*)(wr + o);
                const float* w0 = s_wo + o * 7;
                #pragma unroll
                for (int k = 0; k < 7; ++k)
                    acc[k] = fmaf(wv.x, w0[k], fmaf(wv.y, w0[7+k],
                             fmaf(wv.z, w0[14+k], fmaf(wv.w, w0[21+k], acc[k]))));
            }
        } else if (it < 160) {                    // P4
            int s = it - 64, m = s >> 5, a = s & 31;
            const float* wr = W3_1 + (2048 + a*64 + l) * 32;
            #pragma unroll 4
            for (int o = 0; o < 32; o += 4) {
                float4 wv = *(const float4*)(wr + o);
                const float* w0 = s_wo + (64 + o*3 + m) * 7;
                #pragma unroll
                for (int k = 0; k < 7; ++k)
                    acc[k] = fmaf(wv.x, w0[k], fmaf(wv.y, w0[21+k],
                             fmaf(wv.z, w0[42+k], fmaf(wv.w, w0[63+k], acc[k]))));
            }
        } else {
            int it2 = it - 160, ah = l >> 5, bh = l & 31;
            if (it2 < 16) {                       // P2
                int a = it2*2 + ah;
                const float* wr = W3_0 + (4096 + a*32 + bh) * 64;
                #pragma unroll 4
                for (int o = 0; o < 64; o += 4) {
                    float4 wv = *(const float4*)(wr + o);
                    const float* w0 = s_wo + o * 7;
                    #pragma unroll
                    for (int k = 0; k < 7; ++k)
                        acc[k] = fmaf(wv.x, w0[k], fmaf(wv.y, w0[7+k],
                                 fmaf(wv.z, w0[14+k], fmaf(wv.w, w0[21+k], acc[k]))));
                }
            } else if (it2 < 112) {               // P3
                int u2 = it2 - 16, m = u2 >> 5, a = (u2 & 31)*2 + ah;
                const float* wr = W3_1 + (a*32 + bh) * 32;
                #pragma unroll 4
                for (int o = 0; o < 32; o += 4) {
                    float4 wv = *(const float4*)(wr + o);
                    const float* w0 = s_wo + (64 + o*3 + m) * 7;
                    #pragma unroll
                    for (int k = 0; k < 7; ++k)
                        acc[k] = fmaf(wv.x, w0[k], fmaf(wv.y, w0[21+k],
                                 fmaf(wv.z, w0[42+k], fmaf(wv.w, w0[63+k], acc[k]))));
                }
            } else {                              // P5
                int u2 = it2 - 112, m = u2 >> 4, a = (u2 & 15)*2 + ah;
                const float* wr = W3_2 + (a*32 + bh) * 16;
                #pragma unroll 4
                for (int o = 0; o < 16; o += 4) {
                    float4 wv = *(const float4*)(wr + o);
                    const float* w0 = s_wo + (160 + o*5 + m) * 7;
                    #pragma unroll
                    for (int k = 0; k < 7; ++k)
                        acc[k] = fmaf(wv.x, w0[k], fmaf(wv.y, w0[35+k],
                                 fmaf(wv.z, w0[70+k], fmaf(wv.w, w0[105+k], acc[k]))));
                }
            }
        }
        float* dst = ws + OFF_W2 + (size_t)R * 8;
        *(float4*)dst       = make_float4(acc[0], acc[1], acc[2], acc[3]);
        *(float4*)(dst + 4) = make_float4(acc[4], acc[5], acc[6], 0.f);
        return;
    }

    // ---------------- feature build ----------------
    const int g    = blockIdx.x - 88;
    const int base = g * 8;
    float* feat = ws + OFF_FEAT + (size_t)g * FEAT_STRIDE;
    {
        int d = tid & 63;
        #pragma unroll
        for (int jj = 0; jj < 2; ++jj) {
            int j = (tid >> 6) + jj * 4;
            int n = base + j;
            float px = pos[n*3+0], py = pos[n*3+1], pz = pos[n*3+2];
            float r  = sqrtf(px*px + py*py + pz*pz) + 1e-9f;
            float t0 = r - (5.0f/63.0f) * (float)d;
            s_f0[j][d] = __expf(-4.f * t0 * t0);
        }
        {
            int j = tid >> 5, d1 = tid & 31;
            int n = base + j;
            float px = pos[n*3+0], py = pos[n*3+1], pz = pos[n*3+2];
            float r  = sqrtf(px*px + py*py + pz*pz) + 1e-9f;
            float t1 = r - (5.0f/31.0f) * (float)d1;
            s_f1[j][d1] = __expf(-4.f * t1 * t1);
        }
        if (tid < 8) {
            int n = base + tid;
            float px = pos[n*3+0], py = pos[n*3+1], pz = pos[n*3+2];
            float r  = sqrtf(px*px + py*py + pz*pz) + 1e-9f;
            float iv = 1.0f / r;
            float d0 = py*iv, d1 = pz*iv, d2 = px*iv;       // (y,z,x)
            feat[(192+0)*8 + tid] = d0;
            feat[(192+1)*8 + tid] = d1;
            feat[(192+2)*8 + tid] = d2;
            feat[(192+3)*8 + tid] = NS3 * (d0*d0 + d1*d1 + d2*d2);
            feat[(192+4)*8 + tid] = 2.f*NS2*d2*d0;
            feat[(192+5)*8 + tid] = 2.f*NS2*d0*d1;
            feat[(192+6)*8 + tid] = NS6*(2.f*d1*d1 - d2*d2 - d0*d0);
            feat[(192+7)*8 + tid] = 2.f*NS2*d2*d1;
            feat[(192+8)*8 + tid] = NS2*(d2*d2 - d0*d0);
        }
        if (tid < 56) out[base*7 + tid] = bout[tid % 7];
    }
    __syncthreads();
    {
        int c = tid & 63, jb = tid >> 6;
        float aa0 = 0.f, aa1 = 0.f, ba0 = 0.f, ba1 = 0.f;
        const float* wa = W1_0 + c;
        const float* wb = W2_0 + c;
        #pragma unroll 4
        for (int d = 0; d < 64; ++d) {
            float wav = wa[d*64], wbv = wb[d*64];
            float fA = s_f0[jb][d], fB = s_f0[jb+4][d];
            aa0 = fmaf(fA, wav, aa0);  aa1 = fmaf(fB, wav, aa1);
            ba0 = fmaf(fA, wbv, ba0);  ba1 = fmaf(fB, wbv, ba1);
        }
        feat[c*8 + jb]      = aa0;  feat[c*8 + jb + 4]      = aa1;
        feat[(64+c)*8 + jb] = ba0;  feat[(64+c)*8 + jb + 4] = ba1;

        int c1 = tid & 31, j8 = tid >> 5;
        float aA = 0.f, aB = 0.f;
        const float* wA = W1_1 + c1;
        const float* wB = W2_1 + c1;
        #pragma unroll 4
        for (int d = 0; d < 32; ++d) {
            float f = s_f1[j8][d];
            aA = fmaf(f, wA[d*32], aA);
            aB = fmaf(f, wB[d*32], aB);
        }
        feat[(128+c1)*8 + j8] = aA;
        feat[(160+c1)*8 + j8] = aB;
    }
}

__device__ __forceinline__ int it_of(int i, int stream) {
    return (i < 20) ? (stream*20 + i) : (160 + stream*24 + (i - 20));
}

// grid = (N/8)*2; block (g, cs): 8 nodes, channel-streams cs*4+w per wave.
__global__ __launch_bounds__(256, 4) void main_kernel(
    const float* __restrict__ ws, float* __restrict__ out, int N)
{
    __shared__ __align__(16) float s_ug[544*8];    // iteration-ordered u*geom table
    __shared__ __align__(16) float s_A1[32*8];
    __shared__ __align__(16) float s_geom[9*8];
    __shared__ float s_red[4][56];

    const int tid  = threadIdx.x;
    const int w    = tid >> 6;
    const int lane = tid & 63;
    const int bh   = lane & 31, ah = lane >> 5;
    const int g    = blockIdx.x >> 1;
    const int cs   = blockIdx.x & 1;
    const int base = g * 8;
    const int stream = cs*4 + w;
    const float* feat  = ws + OFF_FEAT + (size_t)g * FEAT_STRIDE;
    const float* wbase = ws + OFF_W2;

    // ---- prefetch ring prologue (pure global, before any barrier) ----
    float4 pa[4], pb[4];
    #pragma unroll
    for (int s = 0; s < 4; ++s) {
        const float* p = wbase + ((size_t)it_of(s, stream) << 9) + (lane << 3);
        pa[s] = *(const float4*)p;
        pb[s] = *(const float4*)(p + 4);
    }

    // ---- stage features ----
    for (int i = tid; i < 128; i += 256) ((float4*)s_ug)[i]  = ((const float4*)feat)[i];   // a0 -> ug[0:64]
    if (tid < 64) ((float4*)s_A1)[tid]  = ((const float4*)(feat + 128*8))[tid];            // A1
    if (tid < 18) ((float4*)s_geom)[tid] = ((const float4*)(feat + 192*8))[tid];           // geom
    float4 b0a = *(const float4*)(feat + (64+lane)*8);
    float4 b0b = *(const float4*)(feat + (64+lane)*8 + 4);
    float4 B1a = *(const float4*)(feat + (160+bh)*8);
    float4 B1b = *(const float4*)(feat + (160+bh)*8 + 4);
    float b0r[8] = {b0a.x,b0a.y,b0a.z,b0a.w,b0b.x,b0b.y,b0b.z,b0b.w};
    float B1r[8] = {B1a.x,B1a.y,B1a.z,B1a.w,B1b.x,B1b.y,B1b.z,B1b.w};
    __syncthreads();

    // ---- build ug rows 64..543 (reads only rows <64 of s_ug, writes >=64: no race) ----
    for (int r = 64 + tid; r < 544; r += 256) {
        const float* u; const float* gs;
        if (r < 160) { int s = r - 64; u = s_A1 + (s & 31)*8; gs = s_geom + (s >> 5)*8; }
        else {
            int s = r - 160, it2 = s >> 1, half = s & 1;
            if (it2 < 16)       { int a = it2*2 + half;                            u = s_A1 + a*8; gs = s_geom + 3*8; }
            else if (it2 < 112) { int u2 = it2-16;  int m = u2>>5; int a=(u2&31)*2+half; u = s_ug + a*8; gs = s_geom + m*8; }
            else                { int u2 = it2-112; int m = u2>>4; int a=(u2&15)*2+half; u = s_A1 + a*8; gs = s_geom + (4+m)*8; }
        }
        #pragma unroll
        for (int j = 0; j < 8; ++j) s_ug[r*8 + j] = u[j] * gs[j];
    }
    __syncthreads();

    float acc[8][7];
    #pragma unroll
    for (int j = 0; j < 8; ++j)
        #pragma unroll
        for (int k = 0; k < 7; ++k) acc[j][k] = 0.f;

    // ---- loop A: b64 iterations (P1, P4), v = b0[lane] ----
    const float* ugA = s_ug + stream*20*8;
    #pragma unroll 4
    for (int i = 0; i < 20; ++i) {
        int s = i & 3;
        float4 wA = pa[s], wB = pb[s];
        const float* pn = wbase + ((size_t)it_of(i + 4, stream) << 9) + (lane << 3);
        pa[s] = *(const float4*)pn;
        pb[s] = *(const float4*)(pn + 4);
        float4 u0 = *(const float4*)(ugA + i*8);
        float4 u1 = *(const float4*)(ugA + i*8 + 4);
        float uv[8] = {u0.x,u0.y,u0.z,u0.w,u1.x,u1.y,u1.z,u1.w};
        float gv[7] = {wA.x,wA.y,wA.z,wA.w,wB.x,wB.y,wB.z};
        #pragma unroll
        for (int j = 0; j < 8; ++j) {
            float p = uv[j] * b0r[j];
            #pragma unroll
            for (int k = 0; k < 7; ++k) acc[j][k] = fmaf(p, gv[k], acc[j][k]);
        }
    }
    // ---- loop B: b32 iterations (P2, P3, P5), v = B1[bh], a-half = ah ----
    const float* ugB = s_ug + (160 + ah)*8 + stream*24*16;
    #pragma unroll 4
    for (int i = 20; i < 44; ++i) {
        int s = i & 3;
        float4 wA = pa[s], wB = pb[s];
        int inext = i + 4; if (inext > 43) inext = 43;
        const float* pn = wbase + ((size_t)it_of(inext, stream) << 9) + (lane << 3);
        pa[s] = *(const float4*)pn;
        pb[s] = *(const float4*)(pn + 4);
        float4 u0 = *(const float4*)(ugB + (i-20)*16);
        float4 u1 = *(const float4*)(ugB + (i-20)*16 + 4);
        float uv[8] = {u0.x,u0.y,u0.z,u0.w,u1.x,u1.y,u1.z,u1.w};
        float gv[7] = {wA.x,wA.y,wA.z,wA.w,wB.x,wB.y,wB.z};
        #pragma unroll
        for (int j = 0; j < 8; ++j) {
            float p = uv[j] * B1r[j];
            #pragma unroll
            for (int k = 0; k < 7; ++k) acc[j][k] = fmaf(p, gv[k], acc[j][k]);
        }
    }

    // ---- reduce 64 lanes -> 4 waves -> atomic ----
    #pragma unroll
    for (int j = 0; j < 8; ++j)
        #pragma unroll
        for (int k = 0; k < 7; ++k) {
            float v = acc[j][k];
            v += __shfl_xor(v, 1, 64);
            v += __shfl_xor(v, 2, 64);
            v += __shfl_xor(v, 4, 64);
            v += __shfl_xor(v, 8, 64);
            v += __shfl_xor(v, 16, 64);
            v += __shfl_xor(v, 32, 64);
            acc[j][k] = v;
        }
    if (lane == 0) {
        #pragma unroll
        for (int j = 0; j < 8; ++j)
            #pragma unroll
            for (int k = 0; k < 7; ++k)
                s_red[w][j*7 + k] = acc[j][k];
    }
    __syncthreads();
    if (tid < 56) {
        float v = s_red[0][tid] + s_red[1][tid] + s_red[2][tid] + s_red[3][tid];
        atomicAdd(&out[base*7 + tid], v);
    }
}

extern "C" void kernel_launch(void* const* d_in, const int* in_sizes, int n_in,
                              void* d_out, int out_size, void* d_ws, size_t ws_size,
                              hipStream_t stream)
{
    const float* pos  = (const float*)d_in[0];
    const float* W1_0 = (const float*)d_in[1];
    const float* W1_1 = (const float*)d_in[2];
    const float* W2_0 = (const float*)d_in[3];
    const float* W2_1 = (const float*)d_in[4];
    const float* W3_0 = (const float*)d_in[5];
    const float* W3_1 = (const float*)d_in[6];
    const float* W3_2 = (const float*)d_in[7];
    const float* Wout = (const float*)d_in[8];
    const float* bout = (const float*)d_in[9];
    float* ws  = (float*)d_ws;
    float* op  = (float*)d_out;
    int N = in_sizes[0] / 3;   // 4096
    int groups = N / 8;

    prep_kernel<<<88 + groups, 256, 0, stream>>>(pos, W1_0, W1_1, W2_0, W2_1,
                                                 W3_0, W3_1, W3_2, Wout, bout, ws, op, N);
    main_kernel<<<groups * 2, 256, 0, stream>>>(ws, op, N);
}

// Round 5
// 120.720 us; speedup vs baseline: 1.5151x; 1.5151x over previous
//
#include <hip/hip_runtime.h>
#include <math.h>

#define NS2 0.70710678118654752440f  // 1/sqrt(2)
#define NS3 0.57735026918962576451f  // 1/sqrt(3)
#define NS6 0.40824829046386301636f  // 1/sqrt(6)

// ws layout (float offsets)
// W2: [352 iterations][64 lanes][8] — iteration-ordered collapsed weights
//   it 0..63    P1: c = it*64+l            v=b0[l], u=a0[it]
//   it 64..159  P4: s=it-64,m=s>>5,a=s&31  v=b0[l], u=A1[a]*d_m
//   it 160..351 b32 (ah=l>>5, bh=l&31), it2=it-160:
//     it2 0..15    P2: a=it2*2+ah            v=B1[bh], u=A1[a]*NS3dd
//     it2 16..111  P3: m=(it2-16)>>5, a=((it2-16)&31)*2+ah   u=a0[a]*d_m
//     it2 112..191 P5: m=(it2-112)>>4, a=((it2-112)&15)*2+ah u=A1[a]*q_m
#define OFF_W2   0
#define OFF_FEAT 180224   // [N/8 groups][208 rows][8]: a0 0-63, b0 64-127, A1 128-159, B1 160-191, geom 192-200
#define FEAT_STRIDE 1664

// prep: blocks 0..87 build W2; blocks 88.. build per-group features + bias-init out
__global__ __launch_bounds__(256) void prep_kernel(
    const float* __restrict__ pos,
    const float* __restrict__ W1_0, const float* __restrict__ W1_1,
    const float* __restrict__ W2_0, const float* __restrict__ W2_1,
    const float* __restrict__ W3_0, const float* __restrict__ W3_1,
    const float* __restrict__ W3_2, const float* __restrict__ Wout,
    const float* __restrict__ bout,
    float* __restrict__ ws, float* __restrict__ out, int N)
{
    __shared__ float s_wo[1680];
    __shared__ float s_f0[8][64];
    __shared__ float s_f1[8][32];
    const int tid = threadIdx.x;

    if (blockIdx.x < 88) {
        for (int i = tid; i < 1680; i += 256) s_wo[i] = Wout[i];
        __syncthreads();
        int R = blockIdx.x * 256 + tid;          // 0..22527
        int it = R >> 6, l = R & 63;
        float acc[7] = {0.f,0.f,0.f,0.f,0.f,0.f,0.f};
        if (it < 64) {                            // P1
            const float* wr = W3_0 + (it*64 + l) * 64;
            #pragma unroll 4
            for (int o = 0; o < 64; o += 4) {
                float4 wv = *(const float4*)(wr + o);
                const float* w0 = s_wo + o * 7;
                #pragma unroll
                for (int k = 0; k < 7; ++k)
                    acc[k] = fmaf(wv.x, w0[k], fmaf(wv.y, w0[7+k],
                             fmaf(wv.z, w0[14+k], fmaf(wv.w, w0[21+k], acc[k]))));
            }
        } else if (it < 160) {                    // P4
            int s = it - 64, m = s >> 5, a = s & 31;
            const float* wr = W3_1 + (2048 + a*64 + l) * 32;
            #pragma unroll 4
            for (int o = 0; o < 32; o += 4) {
                float4 wv = *(const float4*)(wr + o);
                const float* w0 = s_wo + (64 + o*3 + m) * 7;
                #pragma unroll
                for (int k = 0; k < 7; ++k)
                    acc[k] = fmaf(wv.x, w0[k], fmaf(wv.y, w0[21+k],
                             fmaf(wv.z, w0[42+k], fmaf(wv.w, w0[63+k], acc[k]))));
            }
        } else {
            int it2 = it - 160, ah = l >> 5, bh = l & 31;
            if (it2 < 16) {                       // P2
                int a = it2*2 + ah;
                const float* wr = W3_0 + (4096 + a*32 + bh) * 64;
                #pragma unroll 4
                for (int o = 0; o < 64; o += 4) {
                    float4 wv = *(const float4*)(wr + o);
                    const float* w0 = s_wo + o * 7;
                    #pragma unroll
                    for (int k = 0; k < 7; ++k)
                        acc[k] = fmaf(wv.x, w0[k], fmaf(wv.y, w0[7+k],
                                 fmaf(wv.z, w0[14+k], fmaf(wv.w, w0[21+k], acc[k]))));
                }
            } else if (it2 < 112) {               // P3
                int u2 = it2 - 16, m = u2 >> 5, a = (u2 & 31)*2 + ah;
                const float* wr = W3_1 + (a*32 + bh) * 32;
                #pragma unroll 4
                for (int o = 0; o < 32; o += 4) {
                    float4 wv = *(const float4*)(wr + o);
                    const float* w0 = s_wo + (64 + o*3 + m) * 7;
                    #pragma unroll
                    for (int k = 0; k < 7; ++k)
                        acc[k] = fmaf(wv.x, w0[k], fmaf(wv.y, w0[21+k],
                                 fmaf(wv.z, w0[42+k], fmaf(wv.w, w0[63+k], acc[k]))));
                }
            } else {                              // P5
                int u2 = it2 - 112, m = u2 >> 4, a = (u2 & 15)*2 + ah;
                const float* wr = W3_2 + (a*32 + bh) * 16;
                #pragma unroll 4
                for (int o = 0; o < 16; o += 4) {
                    float4 wv = *(const float4*)(wr + o);
                    const float* w0 = s_wo + (160 + o*5 + m) * 7;
                    #pragma unroll
                    for (int k = 0; k < 7; ++k)
                        acc[k] = fmaf(wv.x, w0[k], fmaf(wv.y, w0[35+k],
                                 fmaf(wv.z, w0[70+k], fmaf(wv.w, w0[105+k], acc[k]))));
                }
            }
        }
        float* dst = ws + OFF_W2 + (size_t)R * 8;
        *(float4*)dst       = make_float4(acc[0], acc[1], acc[2], acc[3]);
        *(float4*)(dst + 4) = make_float4(acc[4], acc[5], acc[6], 0.f);
        return;
    }

    // ---------------- feature build ----------------
    const int g    = blockIdx.x - 88;
    const int base = g * 8;
    float* feat = ws + OFF_FEAT + (size_t)g * FEAT_STRIDE;
    {
        int d = tid & 63;
        #pragma unroll
        for (int jj = 0; jj < 2; ++jj) {
            int j = (tid >> 6) + jj * 4;
            int n = base + j;
            float px = pos[n*3+0], py = pos[n*3+1], pz = pos[n*3+2];
            float r  = sqrtf(px*px + py*py + pz*pz) + 1e-9f;
            float t0 = r - (5.0f/63.0f) * (float)d;
            s_f0[j][d] = __expf(-4.f * t0 * t0);
        }
        {
            int j = tid >> 5, d1 = tid & 31;
            int n = base + j;
            float px = pos[n*3+0], py = pos[n*3+1], pz = pos[n*3+2];
            float r  = sqrtf(px*px + py*py + pz*pz) + 1e-9f;
            float t1 = r - (5.0f/31.0f) * (float)d1;
            s_f1[j][d1] = __expf(-4.f * t1 * t1);
        }
        if (tid < 8) {
            int n = base + tid;
            float px = pos[n*3+0], py = pos[n*3+1], pz = pos[n*3+2];
            float r  = sqrtf(px*px + py*py + pz*pz) + 1e-9f;
            float iv = 1.0f / r;
            float d0 = py*iv, d1 = pz*iv, d2 = px*iv;       // (y,z,x)
            feat[(192+0)*8 + tid] = d0;
            feat[(192+1)*8 + tid] = d1;
            feat[(192+2)*8 + tid] = d2;
            feat[(192+3)*8 + tid] = NS3 * (d0*d0 + d1*d1 + d2*d2);
            feat[(192+4)*8 + tid] = 2.f*NS2*d2*d0;
            feat[(192+5)*8 + tid] = 2.f*NS2*d0*d1;
            feat[(192+6)*8 + tid] = NS6*(2.f*d1*d1 - d2*d2 - d0*d0);
            feat[(192+7)*8 + tid] = 2.f*NS2*d2*d1;
            feat[(192+8)*8 + tid] = NS2*(d2*d2 - d0*d0);
        }
        if (tid < 56) out[base*7 + tid] = bout[tid % 7];
    }
    __syncthreads();
    {
        int c = tid & 63, jb = tid >> 6;
        float aa0 = 0.f, aa1 = 0.f, ba0 = 0.f, ba1 = 0.f;
        const float* wa = W1_0 + c;
        const float* wb = W2_0 + c;
        #pragma unroll 4
        for (int d = 0; d < 64; ++d) {
            float wav = wa[d*64], wbv = wb[d*64];
            float fA = s_f0[jb][d], fB = s_f0[jb+4][d];
            aa0 = fmaf(fA, wav, aa0);  aa1 = fmaf(fB, wav, aa1);
            ba0 = fmaf(fA, wbv, ba0);  ba1 = fmaf(fB, wbv, ba1);
        }
        feat[c*8 + jb]      = aa0;  feat[c*8 + jb + 4]      = aa1;
        feat[(64+c)*8 + jb] = ba0;  feat[(64+c)*8 + jb + 4] = ba1;

        int c1 = tid & 31, j8 = tid >> 5;
        float aA = 0.f, aB = 0.f;
        const float* wA = W1_1 + c1;
        const float* wB = W2_1 + c1;
        #pragma unroll 4
        for (int d = 0; d < 32; ++d) {
            float f = s_f1[j8][d];
            aA = fmaf(f, wA[d*32], aA);
            aB = fmaf(f, wB[d*32], aB);
        }
        feat[(128+c1)*8 + j8] = aA;
        feat[(160+c1)*8 + j8] = aB;
    }
}

__device__ __forceinline__ int it_of(int i, int stream) {
    return (i < 20) ? (stream*20 + i) : (160 + stream*24 + (i - 20));
}

// grid = (N/8)*2; block (g, cs): 8 nodes, channel-streams cs*4+w per wave.
// NOTE: no min-waves clamp — R4's (256,4) forced VGPR=64 and spilled 144 MB to scratch.
__global__ __launch_bounds__(256) void main_kernel(
    const float* __restrict__ ws, float* __restrict__ out, int N)
{
    __shared__ __align__(16) float s_ug[544*8];    // iteration-ordered u*geom table
    __shared__ __align__(16) float s_A1[32*8];
    __shared__ __align__(16) float s_geom[9*8];
    __shared__ float s_red[4][56];

    const int tid  = threadIdx.x;
    const int w    = tid >> 6;
    const int lane = tid & 63;
    const int bh   = lane & 31, ah = lane >> 5;
    const int g    = blockIdx.x >> 1;
    const int cs   = blockIdx.x & 1;
    const int base = g * 8;
    const int stream = cs*4 + w;
    const float* feat  = ws + OFF_FEAT + (size_t)g * FEAT_STRIDE;
    const float* wbase = ws + OFF_W2;

    // ---- prefetch ring prologue (pure global, before any barrier) ----
    float4 pa[4], pb[4];
    #pragma unroll
    for (int s = 0; s < 4; ++s) {
        const float* p = wbase + ((size_t)it_of(s, stream) << 9) + (lane << 3);
        pa[s] = *(const float4*)p;
        pb[s] = *(const float4*)(p + 4);
    }

    // ---- stage features ----
    for (int i = tid; i < 128; i += 256) ((float4*)s_ug)[i]  = ((const float4*)feat)[i];   // a0 -> ug rows 0..63
    if (tid < 64) ((float4*)s_A1)[tid]  = ((const float4*)(feat + 128*8))[tid];            // A1
    if (tid < 18) ((float4*)s_geom)[tid] = ((const float4*)(feat + 192*8))[tid];           // geom
    float4 b0a = *(const float4*)(feat + (64+lane)*8);
    float4 b0b = *(const float4*)(feat + (64+lane)*8 + 4);
    float4 B1a = *(const float4*)(feat + (160+bh)*8);
    float4 B1b = *(const float4*)(feat + (160+bh)*8 + 4);
    float b0r[8] = {b0a.x,b0a.y,b0a.z,b0a.w,b0b.x,b0b.y,b0b.z,b0b.w};
    float B1r[8] = {B1a.x,B1a.y,B1a.z,B1a.w,B1b.x,B1b.y,B1b.z,B1b.w};
    __syncthreads();

    // ---- build ug rows 64..543, linear element indexing (conflict-free writes) ----
    // reads only s_ug rows <64, writes rows >=64: no race.
    for (int idx = tid; idx < 480*8; idx += 256) {
        int r = 64 + (idx >> 3), j = idx & 7;
        const float* u; const float* gs;
        if (r < 160) { int s = r - 64; u = s_A1 + (s & 31)*8; gs = s_geom + (s >> 5)*8; }
        else {
            int s = r - 160, it2 = s >> 1, half = s & 1;
            if (it2 < 16)       { int a = it2*2 + half;                                  u = s_A1 + a*8; gs = s_geom + 3*8; }
            else if (it2 < 112) { int u2 = it2-16;  int m = u2>>5; int a=(u2&31)*2+half; u = s_ug + a*8; gs = s_geom + m*8; }
            else                { int u2 = it2-112; int m = u2>>4; int a=(u2&15)*2+half; u = s_A1 + a*8; gs = s_geom + (4+m)*8; }
        }
        s_ug[r*8 + j] = u[j] * gs[j];
    }
    __syncthreads();

    float acc[8][7];
    #pragma unroll
    for (int j = 0; j < 8; ++j)
        #pragma unroll
        for (int k = 0; k < 7; ++k) acc[j][k] = 0.f;

    // ---- loop A: b64 iterations (P1, P4), v = b0[lane] ----
    const float* ugA = s_ug + stream*20*8;
    #pragma unroll 4
    for (int i = 0; i < 20; ++i) {
        int s = i & 3;
        float4 wA = pa[s], wB = pb[s];
        const float* pn = wbase + ((size_t)it_of(i + 4, stream) << 9) + (lane << 3);
        pa[s] = *(const float4*)pn;
        pb[s] = *(const float4*)(pn + 4);
        float4 u0 = *(const float4*)(ugA + i*8);
        float4 u1 = *(const float4*)(ugA + i*8 + 4);
        float uv[8] = {u0.x,u0.y,u0.z,u0.w,u1.x,u1.y,u1.z,u1.w};
        float gv[7] = {wA.x,wA.y,wA.z,wA.w,wB.x,wB.y,wB.z};
        #pragma unroll
        for (int j = 0; j < 8; ++j) {
            float p = uv[j] * b0r[j];
            #pragma unroll
            for (int k = 0; k < 7; ++k) acc[j][k] = fmaf(p, gv[k], acc[j][k]);
        }
    }
    // ---- loop B: b32 iterations (P2, P3, P5), v = B1[bh], a-half = ah ----
    const float* ugB = s_ug + (160 + ah)*8 + stream*24*16;
    #pragma unroll 4
    for (int i = 20; i < 44; ++i) {
        int s = i & 3;
        float4 wA = pa[s], wB = pb[s];
        int inext = i + 4; if (inext > 43) inext = 43;
        const float* pn = wbase + ((size_t)it_of(inext, stream) << 9) + (lane << 3);
        pa[s] = *(const float4*)pn;
        pb[s] = *(const float4*)(pn + 4);
        float4 u0 = *(const float4*)(ugB + (i-20)*16);
        float4 u1 = *(const float4*)(ugB + (i-20)*16 + 4);
        float uv[8] = {u0.x,u0.y,u0.z,u0.w,u1.x,u1.y,u1.z,u1.w};
        float gv[7] = {wA.x,wA.y,wA.z,wA.w,wB.x,wB.y,wB.z};
        #pragma unroll
        for (int j = 0; j < 8; ++j) {
            float p = uv[j] * B1r[j];
            #pragma unroll
            for (int k = 0; k < 7; ++k) acc[j][k] = fmaf(p, gv[k], acc[j][k]);
        }
    }

    // ---- reduce 64 lanes -> 4 waves -> atomic ----
    #pragma unroll
    for (int j = 0; j < 8; ++j)
        #pragma unroll
        for (int k = 0; k < 7; ++k) {
            float v = acc[j][k];
            v += __shfl_xor(v, 1, 64);
            v += __shfl_xor(v, 2, 64);
            v += __shfl_xor(v, 4, 64);
            v += __shfl_xor(v, 8, 64);
            v += __shfl_xor(v, 16, 64);
            v += __shfl_xor(v, 32, 64);
            acc[j][k] = v;
        }
    if (lane == 0) {
        #pragma unroll
        for (int j = 0; j < 8; ++j)
            #pragma unroll
            for (int k = 0; k < 7; ++k)
                s_red[w][j*7 + k] = acc[j][k];
    }
    __syncthreads();
    if (tid < 56) {
        float v = s_red[0][tid] + s_red[1][tid] + s_red[2][tid] + s_red[3][tid];
        atomicAdd(&out[base*7 + tid], v);
    }
}

extern "C" void kernel_launch(void* const* d_in, const int* in_sizes, int n_in,
                              void* d_out, int out_size, void* d_ws, size_t ws_size,
                              hipStream_t stream)
{
    const float* pos  = (const float*)d_in[0];
    const float* W1_0 = (const float*)d_in[1];
    const float* W1_1 = (const float*)d_in[2];
    const float* W2_0 = (const float*)d_in[3];
    const float* W2_1 = (const float*)d_in[4];
    const float* W3_0 = (const float*)d_in[5];
    const float* W3_1 = (const float*)d_in[6];
    const float* W3_2 = (const float*)d_in[7];
    const float* Wout = (const float*)d_in[8];
    const float* bout = (const float*)d_in[9];
    float* ws  = (float*)d_ws;
    float* op  = (float*)d_out;
    int N = in_sizes[0] / 3;   // 4096
    int groups = N / 8;

    prep_kernel<<<88 + groups, 256, 0, stream>>>(pos, W1_0, W1_1, W2_0, W2_1,
                                                 W3_0, W3_1, W3_2, Wout, bout, ws, op, N);
    main_kernel<<<groups * 2, 256, 0, stream>>>(ws, op, N);
}